// Round 2
// baseline (434.217 us; speedup 1.0000x reference)
//
#include <hip/hip_runtime.h>
#include <math.h>

#define T_TOKENS 16384
#define NEXP     64
#define KDIM     4096
#define TM       16                  // tokens per block -> grid 1024
#define ROUNDS   16                  // per-wave K/4=1024, KC=64 per round

typedef _Float16 f16;
typedef f16   f16x2 __attribute__((ext_vector_type(2)));
typedef f16   f16x8 __attribute__((ext_vector_type(8)));
typedef float f32x4 __attribute__((ext_vector_type(4)));

// XOR swizzle on 16B-unit LDS offsets: banks get oct(2b) + k32(1b) mixed in.
__device__ __forceinline__ int swz(int o) {
    return o ^ ((o >> 4) & 3) ^ (((o >> 6) & 1) << 2);
}

// split 8 fp32 -> packed fp16 hi (uint4) and lo*2^11 (uint4)
__device__ __forceinline__ void split8(const float v[8], uint4* ho, uint4* lo) {
    unsigned hu[4], lu[4];
    #pragma unroll
    for (int p = 0; p < 4; ++p) {
        f16x2 h2, l2;
#if __has_builtin(__builtin_amdgcn_cvt_pkrtz)
        h2 = __builtin_bit_cast(f16x2, __builtin_amdgcn_cvt_pkrtz(v[2*p], v[2*p+1]));
#else
        h2.x = (f16)v[2*p]; h2.y = (f16)v[2*p+1];
#endif
        float r0 = (v[2*p]   - (float)h2.x) * 2048.0f;
        float r1 = (v[2*p+1] - (float)h2.y) * 2048.0f;
#if __has_builtin(__builtin_amdgcn_cvt_pkrtz)
        l2 = __builtin_bit_cast(f16x2, __builtin_amdgcn_cvt_pkrtz(r0, r1));
#else
        l2.x = (f16)r0; l2.y = (f16)r1;
#endif
        hu[p] = __builtin_bit_cast(unsigned, h2);
        lu[p] = __builtin_bit_cast(unsigned, l2);
    }
    *ho = make_uint4(hu[0], hu[1], hu[2], hu[3]);
    *lo = make_uint4(lu[0], lu[1], lu[2], lu[3]);
}

__device__ __forceinline__ f16x8 asf16x8(uint4 u) {
    return __builtin_bit_cast(f16x8, u);
}

// ---------------------------------------------------------------------------
// Main: 1024 blocks x 256 thr (4 waves). Block = 16 tokens x 64 experts.
// Wave wid = K-quarter (1024 k). NO workspace: W fp32 is read straight from
// global (L2-resident, 1 MiB) and converted to f16 hi/lo frags inline each
// round. This removes all d_ws usage so the harness's 1-GiB ws re-poison
// fills (~2 x 160 us, ~80% of the previous 396 us) should leave the timed
// region. LDS only transposes x into A-frag layout (swizzled, conflict-free).
// logit*64 = acc_hh + acc_lo/2048  (W scaled x64 at conversion time).
// Round-1 note: resubmission of Round-0 kernel; previous run died on a
// container-acquire infra failure (no compile/correctness signal). Kernel
// audited: all x/W/out accesses in-bounds and 16B-aligned; no ws, no sync
// in kernel_launch.
// ---------------------------------------------------------------------------
__global__ __launch_bounds__(256, 3) void router_mfma(
    const float* __restrict__ x, const float* __restrict__ W,
    float* __restrict__ out)
{
    __shared__ __align__(16) unsigned char xs[16384];   // 2 fmt x 4 w'' x 2 k32 x 64 x 16B
    __shared__ float partial[4][TM][68];                // +pad: conflict-free

    const int tid  = threadIdx.x;
    const int wid  = tid >> 6;
    const int lane = tid & 63;
    const int t0   = blockIdx.x * TM;

    // ---- x staging mapping: slot s in {0,1}: token = s*8 + (tid>>5), oct8 = tid&31
    const int tok_hi = tid >> 5;              // 0..7
    const int oct8   = tid & 31;
    const int xw     = oct8 >> 3;             // staging w'' (K-quarter)
    const int xk32   = (oct8 >> 2) & 1;
    const int xoct   = oct8 & 3;
    const int koff   = (oct8 & 7) * 8;        // k within the 64-k round slice
    const float* xrow[2] = {
        x + (size_t)(t0 + 0 + tok_hi) * KDIM + xw * 1024 + koff,
        x + (size_t)(t0 + 8 + tok_hi) * KDIM + xw * 1024 + koff
    };
    int owr[2];                               // swizzled 16B-unit write offsets (h)
    #pragma unroll
    for (int s = 0; s < 2; ++s) {
        int lane_f = (s * 8 + tok_hi) + 16 * xoct;
        owr[s] = swz(xw * 128 + xk32 * 64 + lane_f);
    }

    // ---- A-frag read offsets (swizzled), per k32 step ----
    int ord[2];
    #pragma unroll
    for (int s = 0; s < 2; ++s) ord[s] = swz(wid * 128 + s * 64 + lane);

    // ---- W fp32 base for this wave's B-frags ----
    // frag (nt,s) elem j: e = nt*16 + (lane&15), k = wid*1024 + r*64 + s*32 + (lane>>4)*8 + j
    const float* wb = W + (lane & 15) * KDIM + wid * 1024 + ((lane >> 4) << 3);

    f32x4 acc_hh[4], acc_lo[4];
    #pragma unroll
    for (int nt = 0; nt < 4; ++nt) {
        acc_hh[nt] = (f32x4){0.f, 0.f, 0.f, 0.f};
        acc_lo[nt] = (f32x4){0.f, 0.f, 0.f, 0.f};
    }

    // prologue: x round 0 -> regs
    float4 xc[2][2], xn[2][2];
    #pragma unroll
    for (int s = 0; s < 2; ++s) {
        xc[s][0] = *(const float4*)(xrow[s]);
        xc[s][1] = *(const float4*)(xrow[s] + 4);
    }

    for (int r = 0; r < ROUNDS; ++r) {
        // ---- convert + write x_r into A-frag LDS (4x b128, swizzled) ----
        #pragma unroll
        for (int s = 0; s < 2; ++s) {
            float v[8] = { xc[s][0].x, xc[s][0].y, xc[s][0].z, xc[s][0].w,
                           xc[s][1].x, xc[s][1].y, xc[s][1].z, xc[s][1].w };
            uint4 ho, lo;
            split8(v, &ho, &lo);
            *(uint4*)(xs + owr[s] * 16)         = ho;
            *(uint4*)(xs + (owr[s] + 512) * 16) = lo;
        }
        __syncthreads();   // B1: xs ready

        // ---- issue W fp32 loads (L2-hot, 16B/lane x16) + x prefetch ----
        float4 wv[16];     // [nt*4 + s*2 + half]: k-offsets {0..3,4..7,32..35,36..39}
        #pragma unroll
        for (int nt = 0; nt < 4; ++nt) {
            const float* p = wb + nt * (16 * KDIM) + r * 64;
            wv[nt*4+0] = *(const float4*)(p);
            wv[nt*4+1] = *(const float4*)(p + 4);
            wv[nt*4+2] = *(const float4*)(p + 32);
            wv[nt*4+3] = *(const float4*)(p + 36);
        }
        if (r + 1 < ROUNDS) {
            #pragma unroll
            for (int s = 0; s < 2; ++s) {
                xn[s][0] = *(const float4*)(xrow[s] + (r + 1) * 64);
                xn[s][1] = *(const float4*)(xrow[s] + (r + 1) * 64 + 4);
            }
        }

        // ---- convert W -> f16 hi/lo frags inline, MFMA: 2 k32 x 4 nt x 3 ----
        #pragma unroll
        for (int s = 0; s < 2; ++s) {
            f16x8 ah = asf16x8(*(const uint4*)(xs + ord[s] * 16));
            f16x8 al = asf16x8(*(const uint4*)(xs + (ord[s] + 512) * 16));
            #pragma unroll
            for (int nt = 0; nt < 4; ++nt) {
                const float4 w0 = wv[nt*4 + s*2];
                const float4 w1 = wv[nt*4 + s*2 + 1];
                float v[8] = { w0.x * 64.f, w0.y * 64.f, w0.z * 64.f, w0.w * 64.f,
                               w1.x * 64.f, w1.y * 64.f, w1.z * 64.f, w1.w * 64.f };
                uint4 bhu, blu;
                split8(v, &bhu, &blu);
                f16x8 bh = asf16x8(bhu);
                f16x8 bl = asf16x8(blu);
                acc_hh[nt] = __builtin_amdgcn_mfma_f32_16x16x32_f16(ah, bh, acc_hh[nt], 0, 0, 0);
                acc_lo[nt] = __builtin_amdgcn_mfma_f32_16x16x32_f16(ah, bl, acc_lo[nt], 0, 0, 0);
                acc_lo[nt] = __builtin_amdgcn_mfma_f32_16x16x32_f16(al, bh, acc_lo[nt], 0, 0, 0);
            }
        }
        __syncthreads();   // B2: xs consumed; drains x(r+1) loads
        #pragma unroll
        for (int s = 0; s < 2; ++s) { xc[s][0] = xn[s][0]; xc[s][1] = xn[s][1]; }
    }

    // ---- epilogue: per-wave partial logits (x64-scaled), cross-wave sum, top-2 ----
    #pragma unroll
    for (int nt = 0; nt < 4; ++nt) {
        #pragma unroll
        for (int rr = 0; rr < 4; ++rr) {
            int token = (lane >> 4) * 4 + rr;          // C/D: col=lane&15,row=(lane>>4)*4+reg
            int e     = nt * 16 + (lane & 15);
            partial[wid][token][e] = acc_hh[nt][rr] + acc_lo[nt][rr] * (1.0f / 2048.0f);
        }
    }
    __syncthreads();

    if (tid < TM) {
        const int t = tid;
        float m1 = -INFINITY, m2 = -INFINITY;
        int i1 = 0, i2 = 0;
        for (int e = 0; e < NEXP; ++e) {
            float v = partial[0][t][e] + partial[1][t][e]
                    + partial[2][t][e] + partial[3][t][e];
            if (v > m1)      { m2 = m1; i2 = i1; m1 = v; i1 = e; }
            else if (v > m2) { m2 = v; i2 = e; }
        }
        float e2 = __expf((m2 - m1) * (1.0f / 64.0f));  // undo x64 W scale
        float denom = 1.f + e2;
        int gt = t0 + t;
        out[gt * 2 + 0] = 1.f / denom;
        out[gt * 2 + 1] = e2 / denom;
        out[2 * T_TOKENS + gt * 2 + 0] = (float)i1;
        out[2 * T_TOKENS + gt * 2 + 1] = (float)i2;
    }
}

extern "C" void kernel_launch(void* const* d_in, const int* in_sizes, int n_in,
                              void* d_out, int out_size, void* d_ws, size_t ws_size,
                              hipStream_t stream) {
    const float* x = (const float*)d_in[0];
    const float* W = (const float*)d_in[1];
    (void)d_ws; (void)ws_size;   // deliberately unused: avoid ws re-poison cost

    router_mfma<<<T_TOKENS / TM, 256, 0, stream>>>(x, W, (float*)d_out);
}

// Round 3
// 363.048 us; speedup vs baseline: 1.1960x; 1.1960x over previous
//
#include <hip/hip_runtime.h>
#include <math.h>

#define T_TOKENS 16384
#define NEXP     64
#define KDIM     4096
#define TMB      64                  // tokens per block -> grid 256
#define ROUNDS   32                  // 128 k per round (64 per K-half wave)

typedef _Float16 f16;
typedef f16   f16x2 __attribute__((ext_vector_type(2)));
typedef f16   f16x8 __attribute__((ext_vector_type(8)));
typedef float f32x4 __attribute__((ext_vector_type(4)));

// split 8 fp32 -> packed fp16 hi (uint4) and lo*2^11 (uint4)
__device__ __forceinline__ void split8(const float v[8], uint4* ho, uint4* lo) {
    unsigned hu[4], lu[4];
    #pragma unroll
    for (int p = 0; p < 4; ++p) {
        f16x2 h2, l2;
#if __has_builtin(__builtin_amdgcn_cvt_pkrtz)
        h2 = __builtin_bit_cast(f16x2, __builtin_amdgcn_cvt_pkrtz(v[2*p], v[2*p+1]));
#else
        h2.x = (f16)v[2*p]; h2.y = (f16)v[2*p+1];
#endif
        float r0 = (v[2*p]   - (float)h2.x) * 2048.0f;
        float r1 = (v[2*p+1] - (float)h2.y) * 2048.0f;
#if __has_builtin(__builtin_amdgcn_cvt_pkrtz)
        l2 = __builtin_bit_cast(f16x2, __builtin_amdgcn_cvt_pkrtz(r0, r1));
#else
        l2.x = (f16)r0; l2.y = (f16)r1;
#endif
        hu[p] = __builtin_bit_cast(unsigned, h2);
        lu[p] = __builtin_bit_cast(unsigned, l2);
    }
    *ho = make_uint4(hu[0], hu[1], hu[2], hu[3]);
    *lo = make_uint4(lu[0], lu[1], lu[2], lu[3]);
}

__device__ __forceinline__ f16x8 asf16x8(uint4 u) {
    return __builtin_bit_cast(f16x8, u);
}

// convert 16 scaled floats (2 groups of 8) -> hi/lo frag writes into LDS region.
// o0/o1: byte offsets of group 0/1 hi-frag; lo-frag lives at +4096 B (fmt bit = +4 frags).
__device__ __forceinline__ void stage8(const float4 c[4], float scale,
                                       unsigned char* base, int o0, int o1) {
    #pragma unroll
    for (int g = 0; g < 2; ++g) {
        float v[8] = { c[2*g].x * scale,   c[2*g].y * scale,
                       c[2*g].z * scale,   c[2*g].w * scale,
                       c[2*g+1].x * scale, c[2*g+1].y * scale,
                       c[2*g+1].z * scale, c[2*g+1].w * scale };
        uint4 ho, lo;
        split8(v, &ho, &lo);
        const int o = g ? o1 : o0;
        *(uint4*)(base + o)        = ho;
        *(uint4*)(base + o + 4096) = lo;
    }
}

// ---------------------------------------------------------------------------
// 256 blocks x 512 thr (8 waves). Block = 64 tokens x 64 experts, full K.
// Wave wid: mt = wid>>1 (token tile, 16 tok), hq = wid&1 (K-half, 2048 k).
// Per round r (k-slice of 128): 512 threads cooperatively stage BOTH the
// x-slice [64 tok][128 k] and W-slice [64 exp][128 k] fp32 -> f16 hi/lo
// MFMA frags in LDS (frag-linear: unit u = f*64+lane, f=((h*2+s)*2+fmt)*4+rt).
// This cuts chip-wide W load+convert 4x vs TM=16 (256 MB vs 1 GB) and feeds
// MFMA operands from LDS instead of scattered per-lane L2 loads.
// Frag layouts identical to the verified Round-0 kernel:
//   A/B lane l, elem j: row = rt*16+(l&15), k = h*64 + s*32 + (l>>4)*8 + j
//   C/D: col(expert) = lane&15, row(token) = (lane>>4)*4 + rr
// logit*64 = acc_hh + acc_lo/2048 (W scaled x64 at conversion).
// ---------------------------------------------------------------------------
__global__ __launch_bounds__(512, 2) void router_mfma(
    const float* __restrict__ x, const float* __restrict__ W,
    float* __restrict__ out)
{
    __shared__ __align__(16) unsigned char sm[65536];
    // [0,32768): x A-frags ; [32768,65536): W B-frags
    // epilogue alias: float partial[2][64][69] (35328 B)

    const int tid  = threadIdx.x;
    const int wid  = tid >> 6;
    const int lane = tid & 63;
    const int mt   = wid >> 1;            // token tile 0..3
    const int hq   = wid & 1;             // K-half 0..1
    const int t0   = blockIdx.x * TMB;

    // ---- cooperative staging identity: 64 B (16 floats) per thread per src ----
    const int srow = tid >> 3;            // 0..63 (token for x, expert for W)
    const int skk  = (tid & 7) * 16;      // k offset within 128-slice
    const float* xsrc = x + (size_t)(t0 + srow) * KDIM + skk;
    const float* wsrc = W + (size_t)srow * KDIM + skk;
    int u0, u1;                           // byte offsets of hi-frag writes (g=0,1)
    {
        #pragma unroll
        for (int g = 0; g < 2; ++g) {
            int kl = skk + g * 8;
            int h  = (kl >> 6) & 1;
            int s5 = (kl >> 5) & 1;
            int j3 = (kl >> 3) & 3;
            int f  = ((h * 2 + s5) * 2 + 0) * 4 + (srow >> 4);
            int u  = (f * 64 + (j3 * 16 + (srow & 15))) * 16;
            if (g == 0) u0 = u; else u1 = u;
        }
    }

    // ---- frag read byte offsets (per s; nt adds 1024 B; lo fmt adds 4096 B) ----
    unsigned char* xsb = sm;
    unsigned char* wsb = sm + 32768;
    int ua[2], ub[2];
    #pragma unroll
    for (int s = 0; s < 2; ++s) {
        ua[s] = ((((hq * 2 + s) * 2 + 0) * 4 + mt) * 64 + lane) * 16;
        ub[s] = ((((hq * 2 + s) * 2 + 0) * 4 + 0 ) * 64 + lane) * 16;
    }

    f32x4 acc_hh[4], acc_lo[4];
    #pragma unroll
    for (int nt = 0; nt < 4; ++nt) {
        acc_hh[nt] = (f32x4){0.f, 0.f, 0.f, 0.f};
        acc_lo[nt] = (f32x4){0.f, 0.f, 0.f, 0.f};
    }

    // prologue: round-0 slices -> regs
    float4 xc[4], wc[4], xn[4], wn[4];
    #pragma unroll
    for (int q = 0; q < 4; ++q) {
        xc[q] = *(const float4*)(xsrc + q * 4);
        wc[q] = *(const float4*)(wsrc + q * 4);
    }

    for (int r = 0; r < ROUNDS; ++r) {
        // ---- convert + write current slices into frag LDS ----
        stage8(xc, 1.0f,  xsb, u0, u1);
        stage8(wc, 64.0f, wsb, u0, u1);
        // ---- issue next-round global loads (land under MFMA section) ----
        if (r + 1 < ROUNDS) {
            const float* xp = xsrc + (r + 1) * 128;
            const float* wp = wsrc + (r + 1) * 128;
            #pragma unroll
            for (int q = 0; q < 4; ++q) {
                xn[q] = *(const float4*)(xp + q * 4);
                wn[q] = *(const float4*)(wp + q * 4);
            }
        }
        __syncthreads();   // B1: frags ready

        // ---- MFMA: 2 k32 steps x 4 ntiles x 3 passes ----
        #pragma unroll
        for (int s = 0; s < 2; ++s) {
            f16x8 ah = asf16x8(*(const uint4*)(xsb + ua[s]));
            f16x8 al = asf16x8(*(const uint4*)(xsb + ua[s] + 4096));
            #pragma unroll
            for (int nt = 0; nt < 4; ++nt) {
                f16x8 bh = asf16x8(*(const uint4*)(wsb + ub[s] + nt * 1024));
                f16x8 bl = asf16x8(*(const uint4*)(wsb + ub[s] + nt * 1024 + 4096));
                acc_hh[nt] = __builtin_amdgcn_mfma_f32_16x16x32_f16(ah, bh, acc_hh[nt], 0, 0, 0);
                acc_lo[nt] = __builtin_amdgcn_mfma_f32_16x16x32_f16(ah, bl, acc_lo[nt], 0, 0, 0);
                acc_lo[nt] = __builtin_amdgcn_mfma_f32_16x16x32_f16(al, bh, acc_lo[nt], 0, 0, 0);
            }
        }
        __syncthreads();   // B2: frags consumed, safe to overwrite next round

        if (r + 1 < ROUNDS) {
            #pragma unroll
            for (int q = 0; q < 4; ++q) { xc[q] = xn[q]; wc[q] = wn[q]; }
        }
    }

    // ---- epilogue: per-K-half partial logits (x64-scaled), 2-way sum, top-2 ----
    float (*partial)[64][69] = (float (*)[64][69])sm;   // aliases staging LDS
    #pragma unroll
    for (int nt = 0; nt < 4; ++nt) {
        #pragma unroll
        for (int rr = 0; rr < 4; ++rr) {
            int token = mt * 16 + (lane >> 4) * 4 + rr;
            int e     = nt * 16 + (lane & 15);
            partial[hq][token][e] = acc_hh[nt][rr] + acc_lo[nt][rr] * (1.0f / 2048.0f);
        }
    }
    __syncthreads();

    if (tid < TMB) {
        const int t = tid;
        float m1 = -INFINITY, m2 = -INFINITY;
        int i1 = 0, i2 = 0;
        for (int e = 0; e < NEXP; ++e) {
            float v = partial[0][t][e] + partial[1][t][e];
            if (v > m1)      { m2 = m1; i2 = i1; m1 = v; i1 = e; }
            else if (v > m2) { m2 = v; i2 = e; }
        }
        float e2 = __expf((m2 - m1) * (1.0f / 64.0f));  // undo x64 W scale
        float denom = 1.f + e2;
        int gt = t0 + t;
        out[gt * 2 + 0] = 1.f / denom;
        out[gt * 2 + 1] = e2 / denom;
        out[2 * T_TOKENS + gt * 2 + 0] = (float)i1;
        out[2 * T_TOKENS + gt * 2 + 1] = (float)i2;
    }
}

extern "C" void kernel_launch(void* const* d_in, const int* in_sizes, int n_in,
                              void* d_out, int out_size, void* d_ws, size_t ws_size,
                              hipStream_t stream) {
    const float* x = (const float*)d_in[0];
    const float* W = (const float*)d_in[1];
    (void)d_ws; (void)ws_size;   // deliberately unused: avoid ws re-poison cost

    router_mfma<<<T_TOKENS / TMB, 512, 0, stream>>>(x, W, (float*)d_out);
}